// Round 1
// baseline (1641.858 us; speedup 1.0000x reference)
//
#include <hip/hip_runtime.h>
#include <stdint.h>
#include <math.h>

#define DD 64
#define K_SOURCE_C 100
#define K_MIN_C 50
#define K_MAX_C 1000
#define L_INFL_C 4
#define A_SLOPE_C 1.0
#define COS_EPS_C 1e-8f

__device__ __forceinline__ uint32_t f2mono(float f) {
    uint32_t u = __float_as_uint(f);
    return (u & 0x80000000u) ? ~u : (u | 0x80000000u);
}

// ---------------- init: sentinels + zeros + K(l) ----------------
__global__ void init_kernel(uint32_t* mx, uint8_t* diff, int* cnt, double* sums,
                            int* Kp, const int* l_ptr, int N, int B) {
    int i = blockIdx.x * blockDim.x + threadIdx.x;
    if (i < N) { mx[i] = 0u; diff[i] = 1; }
    if (i < B) cnt[i] = 0;
    if (i < 4) sums[i] = 0.0;
    if (i == 0) {
        double l = (double)(*l_ptr);
        int K;
        if (l < (double)L_INFL_C) {
            double s = 1.0 / (1.0 + exp(-A_SLOPE_C * (l - L_INFL_C / 2.0)));
            K = (int)(K_SOURCE_C + (K_MAX_C - K_SOURCE_C) * s);
        } else {
            double s = 1.0 / (1.0 + exp(-A_SLOPE_C * (l - 3.0 * L_INFL_C / 2.0)));
            K = (int)(K_MIN_C + (K_MAX_C - K_MIN_C) * (1.0 - s));
        }
        *Kp = K;
    }
}

__global__ void diff_kernel(uint8_t* diff, const int* old_idx, int n_old, int N) {
    int j = blockIdx.x * blockDim.x + threadIdx.x;
    if (j < n_old) { int idx = old_idx[j]; if (idx >= 0 && idx < N) diff[idx] = 0; }
}

// ---------------- per-batch context MLP (rank-B structure) ----------------
__global__ void ctx_kernel(const float* hidden_q, const int* q_rel, const float* rel_embed,
                           const float* w1, const float* b1, const float* w2, const float* b2,
                           const float* expert_emb, const float* w_n,
                           float* escore, float* nscale, float* qvec, float* qnorm, int B) {
    int b = blockIdx.x, t = threadIdx.x;   // 64 threads
    __shared__ float cin[2 * DD];
    __shared__ float h1s[DD];
    int q = q_rel[b];
    float qv = rel_embed[(size_t)q * DD + t];
    qvec[b * DD + t] = qv;
    cin[t] = hidden_q[b * DD + t];
    cin[DD + t] = qv;
    __syncthreads();
    float acc = b1[t];
    for (int j = 0; j < 2 * DD; j++) acc += cin[j] * w1[j * DD + t];
    h1s[t] = fmaxf(acc, 0.f);
    __syncthreads();
    float c = b2[t];
    for (int j = 0; j < DD; j++) c += h1s[j] * w2[j * DD + t];
    float e0 = c * expert_emb[0 * DD + t];
    float e1 = c * expert_emb[1 * DD + t];
    float e2 = c * expert_emb[2 * DD + t];
    float wn = c * w_n[t];
    float qq = qv * qv;
    for (int m = 32; m >= 1; m >>= 1) {
        e0 += __shfl_xor(e0, m); e1 += __shfl_xor(e1, m); e2 += __shfl_xor(e2, m);
        wn += __shfl_xor(wn, m); qq += __shfl_xor(qq, m);
    }
    if (t == 0) {
        escore[b * 3 + 0] = e0; escore[b * 3 + 1] = e1; escore[b * 3 + 2] = e2;
        nscale[b] = fmaxf(wn, 0.f) + log1pf(expf(-fabsf(wn)));   // stable softplus
        qnorm[b] = fmaxf(sqrtf(qq), COS_EPS_C);
    }
}

// ---------------- per-node expert weights -> importance sums + sumsq ----------------
__global__ void weights_kernel(const int* nodes, const float* noise, const float* escore,
                               const float* nscale, double* sums, int N, int B) {
    int i = blockIdx.x * blockDim.x + threadIdx.x;
    double s0 = 0, s1 = 0, s2 = 0, sq = 0;
    if (i < N) {
        int b = nodes[2 * i];
        if (b >= 0 && b < B) {
            float ns = nscale[b];
            float e0 = escore[b * 3 + 0] + noise[3 * i + 0] * ns;
            float e1 = escore[b * 3 + 1] + noise[3 * i + 1] * ns;
            float e2 = escore[b * 3 + 2] + noise[3 * i + 2] * ns;
            float m = fmaxf(e0, fmaxf(e1, e2));
            float x0 = expf(e0 - m), x1 = expf(e1 - m), x2 = expf(e2 - m);
            float s = x0 + x1 + x2;
            x0 /= s; x1 /= s; x2 /= s;
            s0 = x0; s1 = x1; s2 = x2;
            sq = (double)x0 * x0 + (double)x1 * x1 + (double)x2 * x2;
        }
    }
    for (int m = 32; m >= 1; m >>= 1) {
        s0 += __shfl_xor(s0, m); s1 += __shfl_xor(s1, m);
        s2 += __shfl_xor(s2, m); sq += __shfl_xor(sq, m);
    }
    __shared__ double red[4][4];
    int wid = threadIdx.x >> 6, lane = threadIdx.x & 63;
    if (lane == 0) { red[wid][0] = s0; red[wid][1] = s1; red[wid][2] = s2; red[wid][3] = sq; }
    __syncthreads();
    if (threadIdx.x == 0) {
        int nw = blockDim.x >> 6;
        double a0 = 0, a1 = 0, a2 = 0, a3 = 0;
        for (int w = 0; w < nw; w++) { a0 += red[w][0]; a1 += red[w][1]; a2 += red[w][2]; a3 += red[w][3]; }
        atomicAdd(&sums[0], a0); atomicAdd(&sums[1], a1);
        atomicAdd(&sums[2], a2); atomicAdd(&sums[3], a3);
    }
}

__global__ void stats_kernel(const double* sums, float* wvec, float* out_L, int N) {
    double c0 = sums[0], c1 = sums[1], c2 = sums[2], S2 = sums[3];
    double tot = c0 + c1 + c2;
    wvec[0] = (float)(c0 / tot); wvec[1] = (float)(c1 / tot); wvec[2] = (float)(c2 / tot);
    double n = 3.0 * (double)N;
    double mean = tot / n;
    double var = (S2 - tot * tot / n) / (n - 1.0);   // ddof=1
    if (var < 0) var = 0;
    double cv = sqrt(var) / (mean + 1e-5);
    *out_L = (float)(cv * cv);
}

// ---------------- cosine(hidden_i, qn_b): 16 lanes per node ----------------
__global__ void cos_kernel(const float* hidden, const int* nodes, const float* qvec,
                           const float* qnorm, float* cosvals, int N, int B) {
    int t = threadIdx.x;
    int node = blockIdx.x * 16 + (t >> 4);
    int sub = t & 15;
    if (node >= N) return;
    int b = nodes[2 * node];
    float4 h4 = *(const float4*)(hidden + (size_t)node * DD + sub * 4);
    float num = 0.f;
    if (b >= 0 && b < B) {
        float4 q4 = *(const float4*)(qvec + b * DD + sub * 4);
        num = h4.x * q4.x + h4.y * q4.y + h4.z * q4.z + h4.w * q4.w;
    }
    float hs = h4.x * h4.x + h4.y * h4.y + h4.z * h4.z + h4.w * h4.w;
    for (int m = 8; m >= 1; m >>= 1) { num += __shfl_xor(num, m); hs += __shfl_xor(hs, m); }
    if (sub == 0) {
        float qn = (b >= 0 && b < B) ? qnorm[b] : COS_EPS_C;
        cosvals[node] = num / (fmaxf(sqrtf(hs), COS_EPS_C) * qn);
    }
}

// ---------------- segment max via monotone-uint atomicMax ----------------
__global__ void segmax_kernel(const int* edges, const float* alpha_temp, uint32_t* mx,
                              int NE, int N) {
    int e = blockIdx.x * blockDim.x + threadIdx.x;
    if (e < NE) {
        int o = edges[(size_t)e * 6 + 5];
        if (o >= 0 && o < N) atomicMax(&mx[o], f2mono(alpha_temp[e]));
    }
}

// ---------------- compact per-row candidate keys (order-free; key carries tiebreak) ----
__global__ void compact_kernel(const int* nodes, const uint8_t* diff, const float* scores,
                               const float* cosvals, uint64_t* keys0, uint64_t* keys1,
                               int* cnt, int N, int B, int CAP) {
    int i = blockIdx.x * blockDim.x + threadIdx.x;
    if (i >= N) return;
    if (!diff[i]) return;
    int b = nodes[2 * i];
    if (b < 0 || b >= B) return;
    int ei = nodes[2 * i + 1];
    uint64_t tb = (uint64_t)(0xFFFFFFFFu - (uint32_t)ei);
    int pos = atomicAdd(&cnt[b], 1);
    if (pos < CAP) {
        keys0[(size_t)b * CAP + pos] = ((uint64_t)f2mono(scores[i]) << 32) | tb;
        keys1[(size_t)b * CAP + pos] = ((uint64_t)f2mono(cosvals[i]) << 32) | tb;
    }
}

// ---------------- exact K-th largest 64-bit key: radix descent, 13-bit LDS levels ----
__global__ __launch_bounds__(1024)
void select_kernel(const uint64_t* keys0, const uint64_t* keys1, const int* cnt,
                   const uint8_t* diff, const uint32_t* mx, const int* Kp,
                   uint64_t* T, int N, int B, int CAP) {
    __shared__ uint32_t hist[8192];
    __shared__ uint32_t psum[1024];
    __shared__ uint64_t sh_prefix;
    __shared__ uint32_t sh_K;
    __shared__ int sh_found;
    int t = threadIdx.x;
    int sel = blockIdx.x;
    const uint64_t* list = nullptr;
    int n = 0;
    bool scanmode = false;
    if (sel < B) { list = keys0 + (size_t)sel * CAP; n = cnt[sel] < CAP ? cnt[sel] : CAP; }
    else if (sel < 2 * B) { list = keys1 + (size_t)(sel - B) * CAP; n = cnt[sel - B] < CAP ? cnt[sel - B] : CAP; }
    else scanmode = true;
    uint32_t Kr = (uint32_t)(*Kp);
    uint64_t prefix = 0;
    bool done = false, takeall = false;
    const int shifts[5] = {51, 38, 25, 12, 0};
    const int nbits[5]  = {13, 13, 13, 13, 12};
    for (int lev = 0; lev < 5 && !done; lev++) {
        for (int j = t; j < 8192; j += 1024) hist[j] = 0;
        __syncthreads();
        uint64_t pmask = (lev == 0) ? 0ull : (~0ull << shifts[lev - 1]);
        int sh = shifts[lev];
        uint32_t bmask = (1u << nbits[lev]) - 1u;
        if (scanmode) {
            for (int i = t; i < N; i += 1024) {
                if (diff[i]) {
                    uint64_t key = ((uint64_t)mx[i] << 32) | (uint64_t)(0xFFFFFFFFu - (uint32_t)i);
                    if ((key & pmask) == prefix)
                        atomicAdd(&hist[(uint32_t)(key >> sh) & bmask], 1u);
                }
            }
        } else {
            for (int i = t; i < n; i += 1024) {
                uint64_t key = list[i];
                if ((key & pmask) == prefix)
                    atomicAdd(&hist[(uint32_t)(key >> sh) & bmask], 1u);
            }
        }
        __syncthreads();
        uint32_t csum = 0;
#pragma unroll
        for (int j = 0; j < 8; j++) csum += hist[8 * t + j];
        psum[t] = csum;
        __syncthreads();
        for (int off = 1; off < 1024; off <<= 1) {   // inclusive suffix scan
            uint32_t v = (t + off < 1024) ? psum[t + off] : 0u;
            __syncthreads();
            psum[t] += v;
            __syncthreads();
        }
        if (t == 0) sh_found = 0;
        __syncthreads();
        uint32_t total = psum[0];
        if (lev == 0 && total <= Kr) {
            takeall = true; done = true;           // fewer candidates than K: take all
        } else {
            uint32_t g = (t < 1023) ? psum[t + 1] : 0u;   // count in bins strictly above chunk
            int fd = -1; uint32_t fK = 0;
            for (int j = 7; j >= 0; j--) {
                uint32_t h = hist[8 * t + j];
                if (g < Kr && g + h >= Kr) { fd = 8 * t + j; fK = Kr - g; }
                g += h;
            }
            if (fd >= 0) { sh_prefix = prefix | ((uint64_t)fd << sh); sh_K = fK; sh_found = 1; }
            __syncthreads();
            if (sh_found) { prefix = sh_prefix; Kr = sh_K; }
            else { takeall = true; done = true; }
            __syncthreads();
        }
    }
    if (t == 0) T[sel] = takeall ? 0ull : prefix;
}

// ---------------- fused epilogue: masks from thresholds, scale & store ----------------
__global__ void final_kernel(const float* hidden, const float* h0, const float* scores,
                             const int* nodes, const uint8_t* diff, const float* cosvals,
                             const uint32_t* mx, const uint64_t* T, const float* wvec,
                             float* out_hidden, float* out_scores, float* out_h0,
                             int N, int B) {
    int t = threadIdx.x;
    int node = blockIdx.x * 16 + (t >> 4);
    int sub = t & 15;
    if (node >= N) return;
    float w0 = wvec[0], w1 = wvec[1], w2 = wvec[2];
    float wm;
    if (!diff[node]) {
        wm = w0 + w1 + w2;
    } else {
        int b = nodes[2 * node];
        int ei = nodes[2 * node + 1];
        float m0 = 0.f, m1 = 0.f;
        if (b >= 0 && b < B) {
            uint64_t tb = (uint64_t)(0xFFFFFFFFu - (uint32_t)ei);
            uint64_t k0 = ((uint64_t)f2mono(scores[node]) << 32) | tb;
            uint64_t k1 = ((uint64_t)f2mono(cosvals[node]) << 32) | tb;
            m0 = (k0 >= T[b]) ? 1.f : 0.f;
            m1 = (k1 >= T[B + b]) ? 1.f : 0.f;
        }
        uint64_t k2 = ((uint64_t)mx[node] << 32) | (uint64_t)(0xFFFFFFFFu - (uint32_t)node);
        float m2 = (k2 >= T[2 * B]) ? 1.f : 0.f;
        wm = w0 * m0 + w1 * m1 + w2 * m2;
    }
    size_t off = (size_t)node * DD + sub * 4;
    float4 h4 = *(const float4*)(hidden + off);
    float4 g4 = *(const float4*)(h0 + off);
    float4 o1, o2;
    o1.x = h4.x * wm; o1.y = h4.y * wm; o1.z = h4.z * wm; o1.w = h4.w * wm;
    o2.x = g4.x * wm; o2.y = g4.y * wm; o2.z = g4.z * wm; o2.w = g4.w * wm;
    *(float4*)(out_hidden + off) = o1;
    *(float4*)(out_h0 + off) = o2;
    if (sub == 0) out_scores[node] = scores[node] * wm;
}

extern "C" void kernel_launch(void* const* d_in, const int* in_sizes, int n_in,
                              void* d_out, int out_size, void* d_ws, size_t ws_size,
                              hipStream_t stream) {
    const float* hidden     = (const float*)d_in[0];
    const int*   nodes      = (const int*)d_in[1];
    const float* scores     = (const float*)d_in[2];
    const float* h0         = (const float*)d_in[3];
    const float* hidden_q   = (const float*)d_in[5];
    const int*   q_rel      = (const int*)d_in[6];
    const int*   edges      = (const int*)d_in[7];
    const int*   old_idx    = (const int*)d_in[8];
    const float* alpha_temp = (const float*)d_in[12];
    const int*   l_ptr      = (const int*)d_in[13];
    const float* noise      = (const float*)d_in[14];
    const float* mw1        = (const float*)d_in[15];
    const float* mb1        = (const float*)d_in[16];
    const float* mw2        = (const float*)d_in[17];
    const float* mb2        = (const float*)d_in[18];
    const float* rel_embed  = (const float*)d_in[19];
    const float* expert_emb = (const float*)d_in[20];
    const float* w_n        = (const float*)d_in[21];

    int N     = in_sizes[2];
    int NE    = in_sizes[12];
    int n_old = in_sizes[8];
    int B     = in_sizes[5] / DD;
    int CAP   = N / B;

    // workspace layout (16B aligned); key lists placed last with d_out fallback
    size_t off = 0;
    auto take = [&](size_t bytes) -> size_t {
        size_t p = off; off += (bytes + 15) & ~(size_t)15; return p;
    };
    char* wsb = (char*)d_ws;
    float*    cosvals = (float*)   (wsb + take((size_t)N * 4));
    uint32_t* mx      = (uint32_t*)(wsb + take((size_t)N * 4));
    uint8_t*  diff    = (uint8_t*) (wsb + take((size_t)N));
    int*      cnt     = (int*)     (wsb + take((size_t)B * 4));
    double*   sums    = (double*)  (wsb + take(4 * 8));
    int*      Kp      = (int*)     (wsb + take(16));
    float*    escore  = (float*)   (wsb + take((size_t)B * 3 * 4));
    float*    nscale  = (float*)   (wsb + take((size_t)B * 4));
    float*    qvec    = (float*)   (wsb + take((size_t)B * DD * 4));
    float*    qnorm   = (float*)   (wsb + take((size_t)B * 4));
    float*    wvec    = (float*)   (wsb + take(16));
    uint64_t* T       = (uint64_t*)(wsb + take((size_t)(2 * B + 1) * 8));
    size_t keys_bytes = (size_t)B * CAP * 8;
    uint64_t *keys0, *keys1;
    if (ws_size >= off + 2 * keys_bytes) {
        keys0 = (uint64_t*)(wsb + take(keys_bytes));
        keys1 = (uint64_t*)(wsb + take(keys_bytes));
    } else {
        // stage keys in d_out (written by compact, read by select, overwritten by final)
        keys0 = (uint64_t*)d_out;
        keys1 = keys0 + (size_t)B * CAP;
    }

    float* out_hidden = (float*)d_out;
    float* out_scores = out_hidden + (size_t)N * DD;
    float* out_h0     = out_scores + N;
    float* out_L      = out_h0 + (size_t)N * DD;

    int nb = (N + 255) / 256;
    init_kernel<<<nb, 256, 0, stream>>>(mx, diff, cnt, sums, Kp, l_ptr, N, B);
    diff_kernel<<<(n_old + 255) / 256, 256, 0, stream>>>(diff, old_idx, n_old, N);
    ctx_kernel<<<B, 64, 0, stream>>>(hidden_q, q_rel, rel_embed, mw1, mb1, mw2, mb2,
                                     expert_emb, w_n, escore, nscale, qvec, qnorm, B);
    weights_kernel<<<nb, 256, 0, stream>>>(nodes, noise, escore, nscale, sums, N, B);
    stats_kernel<<<1, 1, 0, stream>>>(sums, wvec, out_L, N);
    cos_kernel<<<(N + 15) / 16, 256, 0, stream>>>(hidden, nodes, qvec, qnorm, cosvals, N, B);
    segmax_kernel<<<(NE + 255) / 256, 256, 0, stream>>>(edges, alpha_temp, mx, NE, N);
    compact_kernel<<<nb, 256, 0, stream>>>(nodes, diff, scores, cosvals, keys0, keys1, cnt, N, B, CAP);
    select_kernel<<<2 * B + 1, 1024, 0, stream>>>(keys0, keys1, cnt, diff, mx, Kp, T, N, B, CAP);
    final_kernel<<<(N + 15) / 16, 256, 0, stream>>>(hidden, h0, scores, nodes, diff, cosvals,
                                                    mx, T, wvec, out_hidden, out_scores, out_h0, N, B);
}

// Round 2
// 873.868 us; speedup vs baseline: 1.8788x; 1.8788x over previous
//
#include <hip/hip_runtime.h>
#include <stdint.h>
#include <math.h>

#define DD 64
#define K_SOURCE_C 100
#define K_MIN_C 50
#define K_MAX_C 1000
#define L_INFL_C 4
#define A_SLOPE_C 1.0
#define COS_EPS_C 1e-8f
#define NSEL_MAX 65
#define NBINS 8192

__device__ __forceinline__ uint32_t f2mono(float f) {
    uint32_t u = __float_as_uint(f);
    return (u & 0x80000000u) ? ~u : (u | 0x80000000u);
}

__constant__ int c_shifts[5] = {51, 38, 25, 12, 0};
__constant__ int c_nbits[5]  = {13, 13, 13, 13, 12};

// ---------------- init: sentinels + zeros + K(l) ----------------
__global__ void init_kernel(uint32_t* mx, uint8_t* diff, int* cnt, double* sums,
                            int* Kp, const int* l_ptr, int N, int B) {
    int i = blockIdx.x * blockDim.x + threadIdx.x;
    if (i < N) { mx[i] = 0u; diff[i] = 1; }
    if (i < B) cnt[i] = 0;
    if (i < 4) sums[i] = 0.0;
    if (i == 0) {
        double l = (double)(*l_ptr);
        int K;
        if (l < (double)L_INFL_C) {
            double s = 1.0 / (1.0 + exp(-A_SLOPE_C * (l - L_INFL_C / 2.0)));
            K = (int)(K_SOURCE_C + (K_MAX_C - K_SOURCE_C) * s);
        } else {
            double s = 1.0 / (1.0 + exp(-A_SLOPE_C * (l - 3.0 * L_INFL_C / 2.0)));
            K = (int)(K_MIN_C + (K_MAX_C - K_MIN_C) * (1.0 - s));
        }
        *Kp = K;
    }
}

__global__ void zero_ghist_kernel(uint32_t* ghist, int total) {
    int i = blockIdx.x * blockDim.x + threadIdx.x;
    if (i < total) ghist[i] = 0;
}

__global__ void state_init_kernel(uint64_t* prefix, uint32_t* Krs, uint32_t* done,
                                  const int* Kp, int nsel) {
    int s = threadIdx.x;
    if (s < nsel) { prefix[s] = 0ull; Krs[s] = (uint32_t)(*Kp); done[s] = 0u; }
}

__global__ void diff_kernel(uint8_t* diff, const int* old_idx, int n_old, int N) {
    int j = blockIdx.x * blockDim.x + threadIdx.x;
    if (j < n_old) { int idx = old_idx[j]; if (idx >= 0 && idx < N) diff[idx] = 0; }
}

// ---------------- per-batch context MLP (rank-B structure) ----------------
__global__ void ctx_kernel(const float* hidden_q, const int* q_rel, const float* rel_embed,
                           const float* w1, const float* b1, const float* w2, const float* b2,
                           const float* expert_emb, const float* w_n,
                           float* escore, float* nscale, float* qvec, float* qnorm, int B) {
    int b = blockIdx.x, t = threadIdx.x;   // 64 threads
    __shared__ float cin[2 * DD];
    __shared__ float h1s[DD];
    int q = q_rel[b];
    float qv = rel_embed[(size_t)q * DD + t];
    qvec[b * DD + t] = qv;
    cin[t] = hidden_q[b * DD + t];
    cin[DD + t] = qv;
    __syncthreads();
    float acc = b1[t];
    for (int j = 0; j < 2 * DD; j++) acc += cin[j] * w1[j * DD + t];
    h1s[t] = fmaxf(acc, 0.f);
    __syncthreads();
    float c = b2[t];
    for (int j = 0; j < DD; j++) c += h1s[j] * w2[j * DD + t];
    float e0 = c * expert_emb[0 * DD + t];
    float e1 = c * expert_emb[1 * DD + t];
    float e2 = c * expert_emb[2 * DD + t];
    float wn = c * w_n[t];
    float qq = qv * qv;
    for (int m = 32; m >= 1; m >>= 1) {
        e0 += __shfl_xor(e0, m); e1 += __shfl_xor(e1, m); e2 += __shfl_xor(e2, m);
        wn += __shfl_xor(wn, m); qq += __shfl_xor(qq, m);
    }
    if (t == 0) {
        escore[b * 3 + 0] = e0; escore[b * 3 + 1] = e1; escore[b * 3 + 2] = e2;
        nscale[b] = fmaxf(wn, 0.f) + log1pf(expf(-fabsf(wn)));   // stable softplus
        qnorm[b] = fmaxf(sqrtf(qq), COS_EPS_C);
    }
}

// ---------------- per-node expert weights -> importance sums + sumsq ----------------
__global__ void weights_kernel(const int* nodes, const float* noise, const float* escore,
                               const float* nscale, double* sums, int N, int B) {
    int i = blockIdx.x * blockDim.x + threadIdx.x;
    double s0 = 0, s1 = 0, s2 = 0, sq = 0;
    if (i < N) {
        int b = nodes[2 * i];
        if (b >= 0 && b < B) {
            float ns = nscale[b];
            float e0 = escore[b * 3 + 0] + noise[3 * i + 0] * ns;
            float e1 = escore[b * 3 + 1] + noise[3 * i + 1] * ns;
            float e2 = escore[b * 3 + 2] + noise[3 * i + 2] * ns;
            float m = fmaxf(e0, fmaxf(e1, e2));
            float x0 = expf(e0 - m), x1 = expf(e1 - m), x2 = expf(e2 - m);
            float s = x0 + x1 + x2;
            x0 /= s; x1 /= s; x2 /= s;
            s0 = x0; s1 = x1; s2 = x2;
            sq = (double)x0 * x0 + (double)x1 * x1 + (double)x2 * x2;
        }
    }
    for (int m = 32; m >= 1; m >>= 1) {
        s0 += __shfl_xor(s0, m); s1 += __shfl_xor(s1, m);
        s2 += __shfl_xor(s2, m); sq += __shfl_xor(sq, m);
    }
    __shared__ double red[4][4];
    int wid = threadIdx.x >> 6, lane = threadIdx.x & 63;
    if (lane == 0) { red[wid][0] = s0; red[wid][1] = s1; red[wid][2] = s2; red[wid][3] = sq; }
    __syncthreads();
    if (threadIdx.x == 0) {
        int nw = blockDim.x >> 6;
        double a0 = 0, a1 = 0, a2 = 0, a3 = 0;
        for (int w = 0; w < nw; w++) { a0 += red[w][0]; a1 += red[w][1]; a2 += red[w][2]; a3 += red[w][3]; }
        atomicAdd(&sums[0], a0); atomicAdd(&sums[1], a1);
        atomicAdd(&sums[2], a2); atomicAdd(&sums[3], a3);
    }
}

__global__ void stats_kernel(const double* sums, float* wvec, float* out_L, int N) {
    double c0 = sums[0], c1 = sums[1], c2 = sums[2], S2 = sums[3];
    double tot = c0 + c1 + c2;
    wvec[0] = (float)(c0 / tot); wvec[1] = (float)(c1 / tot); wvec[2] = (float)(c2 / tot);
    double n = 3.0 * (double)N;
    double mean = tot / n;
    double var = (S2 - tot * tot / n) / (n - 1.0);   // ddof=1
    if (var < 0) var = 0;
    double cv = sqrt(var) / (mean + 1e-5);
    *out_L = (float)(cv * cv);
}

// ---------------- cosine(hidden_i, qn_b): 16 lanes per node ----------------
__global__ void cos_kernel(const float* hidden, const int* nodes, const float* qvec,
                           const float* qnorm, float* cosvals, int N, int B) {
    int t = threadIdx.x;
    int node = blockIdx.x * 16 + (t >> 4);
    int sub = t & 15;
    if (node >= N) return;
    int b = nodes[2 * node];
    float4 h4 = *(const float4*)(hidden + (size_t)node * DD + sub * 4);
    float num = 0.f;
    if (b >= 0 && b < B) {
        float4 q4 = *(const float4*)(qvec + b * DD + sub * 4);
        num = h4.x * q4.x + h4.y * q4.y + h4.z * q4.z + h4.w * q4.w;
    }
    float hs = h4.x * h4.x + h4.y * h4.y + h4.z * h4.z + h4.w * h4.w;
    for (int m = 8; m >= 1; m >>= 1) { num += __shfl_xor(num, m); hs += __shfl_xor(hs, m); }
    if (sub == 0) {
        float qn = (b >= 0 && b < B) ? qnorm[b] : COS_EPS_C;
        cosvals[node] = num / (fmaxf(sqrtf(hs), COS_EPS_C) * qn);
    }
}

// ---------------- segment max via monotone-uint atomicMax ----------------
__global__ void segmax_kernel(const int* edges, const float* alpha_temp, uint32_t* mx,
                              int NE, int N) {
    int e = blockIdx.x * blockDim.x + threadIdx.x;
    if (e < NE) {
        int o = edges[(size_t)e * 6 + 5];
        if (o >= 0 && o < N) atomicMax(&mx[o], f2mono(alpha_temp[e]));
    }
}

// ---------------- compact per-row candidate keys; block-aggregated counters ----
__global__ void compact_kernel(const int* nodes, const uint8_t* diff, const float* scores,
                               const float* cosvals, uint64_t* keys0, uint64_t* keys1,
                               int* cnt, int N, int B, int CAP) {
    __shared__ int lcnt[64];
    __shared__ int lbase[64];
    int t = threadIdx.x;
    if (t < B) lcnt[t] = 0;
    __syncthreads();
    int i = blockIdx.x * blockDim.x + t;
    int b = -1, loc = 0;
    if (i < N && diff[i]) {
        int bb = nodes[2 * i];
        if (bb >= 0 && bb < B) { b = bb; loc = atomicAdd(&lcnt[b], 1); }
    }
    __syncthreads();
    if (t < B) lbase[t] = lcnt[t] ? atomicAdd(&cnt[t], lcnt[t]) : 0;
    __syncthreads();
    if (b >= 0) {
        int pos = lbase[b] + loc;
        if (pos < CAP) {
            int ei = nodes[2 * i + 1];
            uint64_t tb = (uint64_t)(0xFFFFFFFFu - (uint32_t)ei);
            keys0[(size_t)b * CAP + pos] = ((uint64_t)f2mono(scores[i]) << 32) | tb;
            keys1[(size_t)b * CAP + pos] = ((uint64_t)f2mono(cosvals[i]) << 32) | tb;
        }
    }
}

// ---------------- per-level histogram: grid-parallel, LDS-privatized ----------------
__global__ __launch_bounds__(1024)
void hist_kernel(const uint64_t* keys0, const uint64_t* keys1, const int* cnt,
                 const uint8_t* diff, const uint32_t* mx,
                 const uint64_t* prefix, const uint32_t* done,
                 uint32_t* ghist, int lev, int N, int B, int CAP) {
    int sel = blockIdx.y;
    if (done[sel]) return;
    __shared__ uint32_t hist[NBINS];
    int t = threadIdx.x;
    for (int j = t; j < NBINS; j += 1024) hist[j] = 0;
    __syncthreads();
    uint64_t pmask = (lev == 0) ? 0ull : (~0ull << c_shifts[lev - 1]);
    uint64_t pref = prefix[sel];
    int sh = c_shifts[lev];
    uint32_t bmask = (1u << c_nbits[lev]) - 1u;
    int stride = gridDim.x * 1024;
    int base = blockIdx.x * 1024 + t;
    if (sel < 2 * B) {
        int row = (sel < B) ? sel : sel - B;
        const uint64_t* list = ((sel < B) ? keys0 : keys1) + (size_t)row * CAP;
        int n = min(cnt[row], CAP);
        for (int i = base; i < n; i += stride) {
            uint64_t key = list[i];
            if ((key & pmask) == pref)
                atomicAdd(&hist[(uint32_t)(key >> sh) & bmask], 1u);
        }
    } else {
        for (int i = base; i < N; i += stride) {
            if (diff[i]) {
                uint64_t key = ((uint64_t)mx[i] << 32) | (uint64_t)(0xFFFFFFFFu - (uint32_t)i);
                if ((key & pmask) == pref)
                    atomicAdd(&hist[(uint32_t)(key >> sh) & bmask], 1u);
            }
        }
    }
    __syncthreads();
    uint32_t* g = ghist + (size_t)sel * NBINS;
    for (int j = t; j < NBINS; j += 1024) {
        uint32_t v = hist[j];
        if (v) atomicAdd(&g[j], v);
    }
}

// ---------------- per-level bin pick: shfl suffix scan, updates state ----------------
__global__ __launch_bounds__(1024)
void pick_kernel(uint32_t* ghist, uint64_t* prefix, uint32_t* Krs, uint32_t* done,
                 uint64_t* T, int lev, int B) {
    int sel = blockIdx.x;
    if (done[sel]) return;
    __shared__ uint32_t hist[NBINS];
    __shared__ uint32_t wtot[16];
    __shared__ uint64_t sh_prefix;
    __shared__ uint32_t sh_K;
    __shared__ int sh_found;
    int t = threadIdx.x;
    uint32_t* g = ghist + (size_t)sel * NBINS;
    uint32_t csum = 0;
#pragma unroll
    for (int j = 0; j < 8; j++) {
        uint32_t v = g[8 * t + j];
        hist[8 * t + j] = v;
        g[8 * t + j] = 0;          // zero for next level
        csum += v;
    }
    // inclusive suffix scan of csum within wave (descending index)
    uint32_t ssum = csum;
    int lane = t & 63, wid = t >> 6;
#pragma unroll
    for (int off = 1; off < 64; off <<= 1) {
        uint32_t v = __shfl_down(ssum, off, 64);
        if (lane + off < 64) ssum += v;
    }
    if (lane == 0) wtot[wid] = ssum;   // total of this wave's chunk
    if (t == 0) sh_found = 0;
    __syncthreads();
    uint32_t above_waves = 0, total = 0;
#pragma unroll
    for (int w = 0; w < 16; w++) {
        uint32_t v = wtot[w];
        total += v;
        if (w > wid) above_waves += v;
    }
    uint32_t suffix_incl = ssum + above_waves;        // count in chunks >= t
    uint32_t Kr = Krs[sel];
    uint64_t pref = prefix[sel];
    int sh = c_shifts[lev];
    if (lev == 0 && total <= Kr) {
        if (t == 0) { T[sel] = 0ull; done[sel] = 1u; }
        return;
    }
    uint32_t gcnt = suffix_incl - csum;               // strictly above this chunk
    int fd = -1; uint32_t fK = 0;
#pragma unroll
    for (int j = 7; j >= 0; j--) {
        uint32_t h = hist[8 * t + j];
        if (gcnt < Kr && gcnt + h >= Kr) { fd = 8 * t + j; fK = Kr - gcnt; }
        gcnt += h;
    }
    if (fd >= 0) { sh_prefix = pref | ((uint64_t)fd << sh); sh_K = fK; sh_found = 1; }
    __syncthreads();
    if (t == 0) {
        if (sh_found) {
            if (lev == 4) { T[sel] = sh_prefix; done[sel] = 1u; }
            else { prefix[sel] = sh_prefix; Krs[sel] = sh_K; }
        } else {
            T[sel] = 0ull; done[sel] = 1u;   // structurally unreachable fallback
        }
    }
}

// ---------------- fused epilogue: masks from thresholds, scale & store ----------------
__global__ void final_kernel(const float* hidden, const float* h0, const float* scores,
                             const int* nodes, const uint8_t* diff, const float* cosvals,
                             const uint32_t* mx, const uint64_t* T, const float* wvec,
                             float* out_hidden, float* out_scores, float* out_h0,
                             int N, int B) {
    int t = threadIdx.x;
    int node = blockIdx.x * 16 + (t >> 4);
    int sub = t & 15;
    if (node >= N) return;
    float w0 = wvec[0], w1 = wvec[1], w2 = wvec[2];
    float wm;
    if (!diff[node]) {
        wm = w0 + w1 + w2;
    } else {
        int b = nodes[2 * node];
        int ei = nodes[2 * node + 1];
        float m0 = 0.f, m1 = 0.f;
        if (b >= 0 && b < B) {
            uint64_t tb = (uint64_t)(0xFFFFFFFFu - (uint32_t)ei);
            uint64_t k0 = ((uint64_t)f2mono(scores[node]) << 32) | tb;
            uint64_t k1 = ((uint64_t)f2mono(cosvals[node]) << 32) | tb;
            m0 = (k0 >= T[b]) ? 1.f : 0.f;
            m1 = (k1 >= T[B + b]) ? 1.f : 0.f;
        }
        uint64_t k2 = ((uint64_t)mx[node] << 32) | (uint64_t)(0xFFFFFFFFu - (uint32_t)node);
        float m2 = (k2 >= T[2 * B]) ? 1.f : 0.f;
        wm = w0 * m0 + w1 * m1 + w2 * m2;
    }
    size_t off = (size_t)node * DD + sub * 4;
    float4 h4 = *(const float4*)(hidden + off);
    float4 g4 = *(const float4*)(h0 + off);
    float4 o1, o2;
    o1.x = h4.x * wm; o1.y = h4.y * wm; o1.z = h4.z * wm; o1.w = h4.w * wm;
    o2.x = g4.x * wm; o2.y = g4.y * wm; o2.z = g4.z * wm; o2.w = g4.w * wm;
    *(float4*)(out_hidden + off) = o1;
    *(float4*)(out_h0 + off) = o2;
    if (sub == 0) out_scores[node] = scores[node] * wm;
}

extern "C" void kernel_launch(void* const* d_in, const int* in_sizes, int n_in,
                              void* d_out, int out_size, void* d_ws, size_t ws_size,
                              hipStream_t stream) {
    const float* hidden     = (const float*)d_in[0];
    const int*   nodes      = (const int*)d_in[1];
    const float* scores     = (const float*)d_in[2];
    const float* h0         = (const float*)d_in[3];
    const float* hidden_q   = (const float*)d_in[5];
    const int*   q_rel      = (const int*)d_in[6];
    const int*   edges      = (const int*)d_in[7];
    const int*   old_idx    = (const int*)d_in[8];
    const float* alpha_temp = (const float*)d_in[12];
    const int*   l_ptr      = (const int*)d_in[13];
    const float* noise      = (const float*)d_in[14];
    const float* mw1        = (const float*)d_in[15];
    const float* mb1        = (const float*)d_in[16];
    const float* mw2        = (const float*)d_in[17];
    const float* mb2        = (const float*)d_in[18];
    const float* rel_embed  = (const float*)d_in[19];
    const float* expert_emb = (const float*)d_in[20];
    const float* w_n        = (const float*)d_in[21];

    int N     = in_sizes[2];
    int NE    = in_sizes[12];
    int n_old = in_sizes[8];
    int B     = in_sizes[5] / DD;
    int CAP   = N / B;
    int nsel  = 2 * B + 1;

    // workspace layout (16B aligned); key lists placed last with d_out fallback
    size_t off = 0;
    auto take = [&](size_t bytes) -> size_t {
        size_t p = off; off += (bytes + 15) & ~(size_t)15; return p;
    };
    char* wsb = (char*)d_ws;
    float*    cosvals = (float*)   (wsb + take((size_t)N * 4));
    uint32_t* mx      = (uint32_t*)(wsb + take((size_t)N * 4));
    uint8_t*  diff    = (uint8_t*) (wsb + take((size_t)N));
    int*      cnt     = (int*)     (wsb + take((size_t)B * 4));
    double*   sums    = (double*)  (wsb + take(4 * 8));
    int*      Kp      = (int*)     (wsb + take(16));
    float*    escore  = (float*)   (wsb + take((size_t)B * 3 * 4));
    float*    nscale  = (float*)   (wsb + take((size_t)B * 4));
    float*    qvec    = (float*)   (wsb + take((size_t)B * DD * 4));
    float*    qnorm   = (float*)   (wsb + take((size_t)B * 4));
    float*    wvec    = (float*)   (wsb + take(16));
    uint64_t* T       = (uint64_t*)(wsb + take((size_t)nsel * 8));
    uint64_t* prefix  = (uint64_t*)(wsb + take((size_t)nsel * 8));
    uint32_t* Krs     = (uint32_t*)(wsb + take((size_t)nsel * 4));
    uint32_t* done    = (uint32_t*)(wsb + take((size_t)nsel * 4));
    uint32_t* ghist   = (uint32_t*)(wsb + take((size_t)nsel * NBINS * 4));
    size_t keys_bytes = (size_t)B * CAP * 8;
    uint64_t *keys0, *keys1;
    if (ws_size >= off + 2 * keys_bytes) {
        keys0 = (uint64_t*)(wsb + take(keys_bytes));
        keys1 = (uint64_t*)(wsb + take(keys_bytes));
    } else {
        // stage keys in d_out (written by compact, read by hist, overwritten by final)
        keys0 = (uint64_t*)d_out;
        keys1 = keys0 + (size_t)B * CAP;
    }

    float* out_hidden = (float*)d_out;
    float* out_scores = out_hidden + (size_t)N * DD;
    float* out_h0     = out_scores + N;
    float* out_L      = out_h0 + (size_t)N * DD;

    int nb = (N + 255) / 256;
    init_kernel<<<nb, 256, 0, stream>>>(mx, diff, cnt, sums, Kp, l_ptr, N, B);
    zero_ghist_kernel<<<(nsel * NBINS + 1023) / 1024, 1024, 0, stream>>>(ghist, nsel * NBINS);
    state_init_kernel<<<1, 128, 0, stream>>>(prefix, Krs, done, Kp, nsel);
    diff_kernel<<<(n_old + 255) / 256, 256, 0, stream>>>(diff, old_idx, n_old, N);
    ctx_kernel<<<B, 64, 0, stream>>>(hidden_q, q_rel, rel_embed, mw1, mb1, mw2, mb2,
                                     expert_emb, w_n, escore, nscale, qvec, qnorm, B);
    weights_kernel<<<nb, 256, 0, stream>>>(nodes, noise, escore, nscale, sums, N, B);
    stats_kernel<<<1, 1, 0, stream>>>(sums, wvec, out_L, N);
    cos_kernel<<<(N + 15) / 16, 256, 0, stream>>>(hidden, nodes, qvec, qnorm, cosvals, N, B);
    segmax_kernel<<<(NE + 255) / 256, 256, 0, stream>>>(edges, alpha_temp, mx, NE, N);
    compact_kernel<<<nb, 256, 0, stream>>>(nodes, diff, scores, cosvals, keys0, keys1, cnt, N, B, CAP);
    dim3 hgrid(64, nsel);
    for (int lev = 0; lev < 5; lev++) {
        hist_kernel<<<hgrid, 1024, 0, stream>>>(keys0, keys1, cnt, diff, mx,
                                                prefix, done, ghist, lev, N, B, CAP);
        pick_kernel<<<nsel, 1024, 0, stream>>>(ghist, prefix, Krs, done, T, lev, B);
    }
    final_kernel<<<(N + 15) / 16, 256, 0, stream>>>(hidden, h0, scores, nodes, diff, cosvals,
                                                    mx, T, wvec, out_hidden, out_scores, out_h0, N, B);
}